// Round 1
// baseline (5028.350 us; speedup 1.0000x reference)
//
#include <hip/hip_runtime.h>

#define T_STEPS 512
#define D_IN    64
#define NW      80   // per-thread weight register floats
#define NB      12   // per-thread bias register floats (3 x float4 slots)

// ---------------------------------------------------------------------------
// Section table (all compile-time):
//   sec  role   G   K  klen kc  threads  tid-range   Wslot  Bslot  gate-base
//   s0   ih0    96  64   8   8   192      0-191      A[0]   0      0
//   s1   hh0    96  32   8   4    96    192-287      A[0]   0      96
//   s2   ih1    48  32   4   8    96    192-287      B[32]  4      192
//   s3   hh1    48  16   8   2    24    288-311      A[0]   0      240
//   s4   ih2    24  16   4   4    24     96-119      B[32]  4      288
//   s5   hh2    24   8   8   1     6    312-317      A[0]   0      312
//   s6   ih3    48   8   4   2    24    120-143      B[32]  4      336
//   s7   hh3    48  16   8   2    24    288-311      B[32]  4      384
//   s8   ih4    96  16   4   4    96    144-239      C[64]  8      432
//   s9   hh4    96  32   8   4    96      0-95       B[32]  4      528
//   s10  out    64  32   4   8   128      0-127      C[64]  8      (global)
// Per-thread W slots are disjoint for every tid (checked by range).
// ---------------------------------------------------------------------------

__device__ __forceinline__ float sigmoid_f(float x) {
    return 1.0f / (1.0f + __expf(-x));
}
__device__ __forceinline__ float tanh_f(float x) {
    // 1 - 2/(e^{2x}+1): correct saturation at +/-inf
    return 1.0f - 2.0f / (__expf(2.0f * x) + 1.0f);
}

template<int WOFF, int BOFF, int KLEN, int KC>
__device__ __forceinline__ void load_sec(float (&wr)[NW], float (&bs)[NB], int local,
                                         const float* __restrict__ W,
                                         const float* __restrict__ bv, int K)
{
    const int gb  = local / KC;
    const int kci = local % KC;
    const int g0  = gb * 4;
    const int k0  = kci * KLEN;
#pragma unroll
    for (int j = 0; j < 4; ++j) {
#pragma unroll
        for (int kk = 0; kk < KLEN; ++kk)
            wr[WOFF + j * KLEN + kk] = W[(g0 + j) * K + (k0 + kk)];
        bs[BOFF + j] = bv[g0 + j];
    }
}

// GEMM over one section: acc[4 gates][4 batch], input vector broadcast from LDS,
// weights from registers, butterfly k-reduction over KC lanes, leader writes LDS.
template<int WOFF, int KLEN, int KC>
__device__ __forceinline__ void gemm_sec(const float (&wr)[NW], const float* bias4,
                                         int local, const float* __restrict__ inv,
                                         float* __restrict__ gate, int gbase)
{
    const int gb  = local / KC;
    const int kci = local % KC;
    const int g0  = gb * 4;
    const int k0  = kci * KLEN;
    float acc[4][4];
#pragma unroll
    for (int j = 0; j < 4; ++j) {
        const float bj = (kci == 0) ? bias4[j] : 0.0f;
#pragma unroll
        for (int b = 0; b < 4; ++b) acc[j][b] = bj;
    }
#pragma unroll
    for (int kk = 0; kk < KLEN; ++kk) {
        const float4 v = *(const float4*)&inv[(k0 + kk) * 4];  // broadcast read
#pragma unroll
        for (int j = 0; j < 4; ++j) {
            const float w = wr[WOFF + j * KLEN + kk];
            acc[j][0] += w * v.x;
            acc[j][1] += w * v.y;
            acc[j][2] += w * v.z;
            acc[j][3] += w * v.w;
        }
    }
#pragma unroll
    for (int m = 1; m < KC; m <<= 1)
#pragma unroll
        for (int j = 0; j < 4; ++j)
#pragma unroll
            for (int b = 0; b < 4; ++b)
                acc[j][b] += __shfl_xor(acc[j][b], m, 64);
    if (kci == 0) {
#pragma unroll
        for (int j = 0; j < 4; ++j) {
            float4 o = {acc[j][0], acc[j][1], acc[j][2], acc[j][3]};
            *(float4*)&gate[(gbase + g0 + j) * 4] = o;
        }
    }
}

// Output projection section: same as gemm_sec but leader stores to global.
template<int WOFF, int KLEN, int KC>
__device__ __forceinline__ void out_sec(const float (&wr)[NW], const float* bias4,
                                        int local, const float* __restrict__ inv,
                                        float* __restrict__ outp /* + (b0*T + t)*64 */)
{
    const int gb  = local / KC;
    const int kci = local % KC;
    const int g0  = gb * 4;
    const int k0  = kci * KLEN;
    float acc[4][4];
#pragma unroll
    for (int j = 0; j < 4; ++j) {
        const float bj = (kci == 0) ? bias4[j] : 0.0f;
#pragma unroll
        for (int b = 0; b < 4; ++b) acc[j][b] = bj;
    }
#pragma unroll
    for (int kk = 0; kk < KLEN; ++kk) {
        const float4 v = *(const float4*)&inv[(k0 + kk) * 4];
#pragma unroll
        for (int j = 0; j < 4; ++j) {
            const float w = wr[WOFF + j * KLEN + kk];
            acc[j][0] += w * v.x;
            acc[j][1] += w * v.y;
            acc[j][2] += w * v.z;
            acc[j][3] += w * v.w;
        }
    }
#pragma unroll
    for (int m = 1; m < KC; m <<= 1)
#pragma unroll
        for (int j = 0; j < 4; ++j)
#pragma unroll
            for (int b = 0; b < 4; ++b)
                acc[j][b] += __shfl_xor(acc[j][b], m, 64);
    if (kci == 0) {
#pragma unroll
        for (int b = 0; b < 4; ++b) {
            float4 o = {acc[0][b], acc[1][b], acc[2][b], acc[3][b]};
            *(float4*)&outp[(size_t)b * (T_STEPS * 64) + g0] = o;
        }
    }
}

// GRU gate combine + state update for one layer. tid in [0, H*4).
__device__ __forceinline__ void upd(int tid, int H, float* __restrict__ hrow,
                                    const float* __restrict__ gate, int ihb, int hhb)
{
    if (tid < H * 4) {
        const int h = tid >> 2, b = tid & 3;
        const float ir = gate[(ihb + h) * 4 + b];
        const float hr = gate[(hhb + h) * 4 + b];
        const float iz = gate[(ihb + H + h) * 4 + b];
        const float hz = gate[(hhb + H + h) * 4 + b];
        const float in_ = gate[(ihb + 2 * H + h) * 4 + b];
        const float hn  = gate[(hhb + 2 * H + h) * 4 + b];
        const float r = sigmoid_f(ir + hr);
        const float z = sigmoid_f(iz + hz);
        const float n = tanh_f(in_ + r * hn);
        const float ho = hrow[h * 4 + b];
        hrow[h * 4 + b] = (1.0f - z) * n + z * ho;
    }
}

__global__ __launch_bounds__(320)
void gru_kernel(const float* __restrict__ X,
                const float* wih0, const float* whh0, const float* bih0, const float* bhh0,
                const float* wih1, const float* whh1, const float* bih1, const float* bhh1,
                const float* wih2, const float* whh2, const float* bih2, const float* bhh2,
                const float* wih3, const float* whh3, const float* bih3, const float* bhh3,
                const float* wih4, const float* whh4, const float* bih4, const float* bhh4,
                const float* wout, const float* bout,
                float* __restrict__ out)
{
    __shared__ __align__(16) float inv0[D_IN * 4];     // x(t) tile, [d][b]
    __shared__ __align__(16) float hbuf[5][32 * 4];    // h states, [l][h][b] (padded to 32)
    __shared__ __align__(16) float gate[624 * 4];      // reduced gate partials, [row][b]

    const int tid = threadIdx.x;
    const int b0  = blockIdx.x * 4;

    float wr[NW];
    float bs[NB];

    // ---- startup: load per-thread weight slices into registers ----
    // Slot A [0:32)
    if      (tid < 192) load_sec<0, 0, 8, 8>(wr, bs, tid,       wih0, bih0, 64);  // s0
    else if (tid < 288) load_sec<0, 0, 8, 4>(wr, bs, tid - 192, whh0, bhh0, 32);  // s1
    else if (tid < 312) load_sec<0, 0, 8, 2>(wr, bs, tid - 288, whh1, bhh1, 16);  // s3
    else if (tid < 318) load_sec<0, 0, 8, 1>(wr, bs, tid - 312, whh2, bhh2, 8);   // s5
    // Slot B [32:64)
    if      (tid < 96)                 load_sec<32, 4, 8, 4>(wr, bs, tid,       whh4, bhh4, 32); // s9
    else if (tid < 120)                load_sec<32, 4, 4, 4>(wr, bs, tid - 96,  wih2, bih2, 16); // s4
    else if (tid < 144)                load_sec<32, 4, 4, 2>(wr, bs, tid - 120, wih3, bih3, 8);  // s6
    else if (tid >= 192 && tid < 288)  load_sec<32, 4, 4, 8>(wr, bs, tid - 192, wih1, bih1, 32); // s2
    else if (tid >= 288 && tid < 312)  load_sec<32, 4, 8, 2>(wr, bs, tid - 288, whh3, bhh3, 16); // s7
    // Slot C [64:80)
    if      (tid < 128)                load_sec<64, 8, 4, 8>(wr, bs, tid,       wout, bout, 32); // s10
    else if (tid >= 144 && tid < 240)  load_sec<64, 8, 4, 4>(wr, bs, tid - 144, wih4, bih4, 16); // s8

    // ---- zero hidden states, stage x(t=0) ----
    for (int i = tid; i < 5 * 32 * 4; i += 320) ((float*)hbuf)[i] = 0.0f;
    for (int e = tid; e < 4 * D_IN; e += 320) {
        const int b = e >> 6, d = e & 63;
        inv0[d * 4 + b] = X[(size_t)(b0 + b) * (T_STEPS * D_IN) + d];
    }
    __syncthreads();

    float xpre[3];

    for (int t = 0; t < T_STEPS; ++t) {
        // ---- P0: ih0 + all hh that read old states (hh0, hh1, hh2) ----
        if      (tid < 192) gemm_sec<0, 8, 8>(wr, &bs[0], tid,       inv0,    gate, 0);    // s0
        else if (tid < 288) gemm_sec<0, 8, 4>(wr, &bs[0], tid - 192, hbuf[0], gate, 96);   // s1
        else if (tid < 312) gemm_sec<0, 8, 2>(wr, &bs[0], tid - 288, hbuf[1], gate, 240);  // s3
        else if (tid < 318) gemm_sec<0, 8, 1>(wr, &bs[0], tid - 312, hbuf[2], gate, 312);  // s5
        __syncthreads();
        upd(tid, 32, hbuf[0], gate, 0, 96);                                                // U0
        __syncthreads();
        // ---- G1: ih1 (needs h0 new), hh3, hh4 (old states); x(t+1) prefetch ----
        if      (tid < 96)                gemm_sec<32, 8, 4>(wr, &bs[4], tid,       hbuf[4], gate, 528); // s9
        else if (tid >= 192 && tid < 288) gemm_sec<32, 4, 8>(wr, &bs[4], tid - 192, hbuf[0], gate, 192); // s2
        else if (tid >= 288 && tid < 312) gemm_sec<32, 8, 2>(wr, &bs[4], tid - 288, hbuf[3], gate, 384); // s7
        if (t + 1 < T_STEPS && tid >= 96 && tid < 192) {
            const int i = tid - 96;
#pragma unroll
            for (int j = 0; j < 3; ++j) {
                const int e = i + 96 * j;
                if (e < 4 * D_IN) {
                    const int b = e >> 6, d = e & 63;
                    xpre[j] = X[(size_t)(b0 + b) * (T_STEPS * D_IN) + (size_t)(t + 1) * D_IN + d];
                }
            }
        }
        __syncthreads();
        upd(tid, 16, hbuf[1], gate, 192, 240);                                             // U1
        __syncthreads();
        if (tid >= 96 && tid < 120) gemm_sec<32, 4, 4>(wr, &bs[4], tid - 96, hbuf[1], gate, 288);  // s4
        __syncthreads();
        upd(tid, 8, hbuf[2], gate, 288, 312);                                              // U2
        __syncthreads();
        if (tid >= 120 && tid < 144) gemm_sec<32, 4, 2>(wr, &bs[4], tid - 120, hbuf[2], gate, 336); // s6
        __syncthreads();
        upd(tid, 16, hbuf[3], gate, 336, 384);                                             // U3
        __syncthreads();
        if (tid >= 144 && tid < 240) gemm_sec<64, 4, 4>(wr, &bs[8], tid - 144, hbuf[3], gate, 432); // s8
        __syncthreads();
        upd(tid, 32, hbuf[4], gate, 432, 528);                                             // U4
        __syncthreads();
        // ---- OUT: projection from h4 + commit x(t+1) to LDS ----
        if (tid < 128)
            out_sec<64, 4, 8>(wr, &bs[8], tid, hbuf[4],
                              out + ((size_t)b0 * T_STEPS + t) * 64);                      // s10
        if (t + 1 < T_STEPS && tid >= 96 && tid < 192) {
            const int i = tid - 96;
#pragma unroll
            for (int j = 0; j < 3; ++j) {
                const int e = i + 96 * j;
                if (e < 4 * D_IN) {
                    const int b = e >> 6, d = e & 63;
                    inv0[d * 4 + b] = xpre[j];
                }
            }
        }
        __syncthreads();
    }
}

extern "C" void kernel_launch(void* const* d_in, const int* in_sizes, int n_in,
                              void* d_out, int out_size, void* d_ws, size_t ws_size,
                              hipStream_t stream)
{
    const float* X = (const float*)d_in[0];
    const float* wih[5]; const float* whh[5]; const float* bih[5]; const float* bhh[5];
    for (int l = 0; l < 5; ++l) {
        wih[l] = (const float*)d_in[1 + 4 * l];
        whh[l] = (const float*)d_in[2 + 4 * l];
        bih[l] = (const float*)d_in[3 + 4 * l];
        bhh[l] = (const float*)d_in[4 + 4 * l];
    }
    const float* wout = (const float*)d_in[21];
    const float* bout = (const float*)d_in[22];

    gru_kernel<<<256, 320, 0, stream>>>(
        X,
        wih[0], whh[0], bih[0], bhh[0],
        wih[1], whh[1], bih[1], bhh[1],
        wih[2], whh[2], bih[2], bhh[2],
        wih[3], whh[3], bih[3], bhh[3],
        wih[4], whh[4], bih[4], bhh[4],
        wout, bout,
        (float*)d_out);
}